// Round 1
// baseline (746.206 us; speedup 1.0000x reference)
//
#include <hip/hip_runtime.h>
#include <stdint.h>

// GATConv fused: softmax(QK^T + adjacency mask) @ V, flash-style, split-bf16 MFMA.
// ws layout (needs ~62 MB):
//   Xh 0-4MB, Xl 4-8, WtH 8-8.5, WtL 8.5-9, Qh 9-13, Ql 13-17, Kh 17-21, Kl 21-25,
//   Vt 25-29, pO 29-61, pM 61-61.25, pL 61.25-61.5

typedef unsigned short u16;
typedef __attribute__((ext_vector_type(8))) short bf16x8;
typedef __attribute__((ext_vector_type(4))) float f32x4;

#define NN 8192
#define DD 256
#define BR 64
#define BC 64
#define CCH 4
#define COLS (NN / CCH)   // 2048
#define NIT (COLS / BC)   // 32

#define MFMA16(a, b, c) __builtin_amdgcn_mfma_f32_16x16x32_bf16((a), (b), (c), 0, 0, 0)

__device__ __forceinline__ u16 f2bf(float f) {
    unsigned u = __float_as_uint(f);
    unsigned r = (u + 0x7fffu + ((u >> 16) & 1u)) >> 16;
    return (u16)r;
}
__device__ __forceinline__ float bf2f(u16 h) { return __uint_as_float(((unsigned)h) << 16); }

__device__ __forceinline__ void gl2lds16(const u16* g, u16* l) {
    __builtin_amdgcn_global_load_lds(
        (const __attribute__((address_space(1))) unsigned int*)g,
        (__attribute__((address_space(3))) unsigned int*)l, 16, 0, 0);
}

// ---------------- split kernels ----------------
__global__ void splitX_kernel(const float* __restrict__ X, u16* __restrict__ Xh,
                              u16* __restrict__ Xl, int n) {
    int i = blockIdx.x * blockDim.x + threadIdx.x;
    if (i < n) {
        float x = X[i];
        u16 h = f2bf(x);
        Xh[i] = h;
        Xl[i] = f2bf(x - bf2f(h));
    }
}

// W[k][n] (3 mats of 256x256) -> Wt[(mat*256+n)][k] hi/lo (transposed for B-frag reads)
__global__ void splitW_kernel(const float* __restrict__ Wq, const float* __restrict__ Wk,
                              const float* __restrict__ Wv, u16* __restrict__ WtH,
                              u16* __restrict__ WtL) {
    int i = blockIdx.x * blockDim.x + threadIdx.x;  // 3*65536
    const int mat = i >> 16;
    const int k = (i >> 8) & 255;
    const int n = i & 255;
    const float* W = (mat == 0) ? Wq : ((mat == 1) ? Wk : Wv);
    float v = W[k * 256 + n];
    u16 h = f2bf(v);
    size_t o = (size_t)(mat * 256 + n) * 256 + k;
    WtH[o] = h;
    WtL[o] = f2bf(v - bf2f(h));
}

// ---------------- QKV GEMM (split-bf16, fp32-accurate) ----------------
// grid (128 row-tiles, 12 n-tiles of combined [Q|K|V] 768 cols). 4 waves, wave = 16 rows x 64 cols.
__global__ __launch_bounds__(256) void qkv_kernel(
    const u16* __restrict__ Xh, const u16* __restrict__ Xl,
    const u16* __restrict__ WtH, const u16* __restrict__ WtL,
    u16* __restrict__ Qh, u16* __restrict__ Ql,
    u16* __restrict__ Kh, u16* __restrict__ Kl,
    u16* __restrict__ Vt) {
    const int lane = threadIdx.x & 63;
    const int w = threadIdx.x >> 6;
    const int l15 = lane & 15;
    const int quad = lane >> 4;
    const int r0 = blockIdx.x * 64;
    const int n0 = blockIdx.y * 64;

    const f32x4 fzero = {0.f, 0.f, 0.f, 0.f};
    f32x4 acc[4];
#pragma unroll
    for (int nt = 0; nt < 4; ++nt) acc[nt] = fzero;

    const size_t xbase = (size_t)(r0 + w * 16 + l15) * DD + quad * 8;
#pragma unroll
    for (int ks = 0; ks < 8; ++ks) {
        const bf16x8 xh = *(const bf16x8*)(Xh + xbase + ks * 32);
        const bf16x8 xl = *(const bf16x8*)(Xl + xbase + ks * 32);
#pragma unroll
        for (int nt = 0; nt < 4; ++nt) {
            const size_t wo = (size_t)(n0 + nt * 16 + l15) * DD + ks * 32 + quad * 8;
            const bf16x8 wh = *(const bf16x8*)(WtH + wo);
            const bf16x8 wl = *(const bf16x8*)(WtL + wo);
            acc[nt] = MFMA16(xh, wh, acc[nt]);
            acc[nt] = MFMA16(xh, wl, acc[nt]);
            acc[nt] = MFMA16(xl, wh, acc[nt]);
        }
    }

    const int mat = n0 >> 8;       // 0=Q, 1=K, 2=V
    const int nc0 = n0 & 255;
    const int orow = r0 + w * 16 + quad * 4;  // C-layout row = quad*4+reg
    if (mat == 2) {
        // V stored transposed: Vt[n][row], pack 4 consecutive rows -> 8B store
#pragma unroll
        for (int nt = 0; nt < 4; ++nt) {
            ushort4 v;
            v.x = f2bf(acc[nt][0]);
            v.y = f2bf(acc[nt][1]);
            v.z = f2bf(acc[nt][2]);
            v.w = f2bf(acc[nt][3]);
            *(ushort4*)(Vt + (size_t)(nc0 + nt * 16 + l15) * NN + orow) = v;
        }
    } else {
        u16* H = mat ? Kh : Qh;
        u16* L = mat ? Kl : Ql;
#pragma unroll
        for (int nt = 0; nt < 4; ++nt)
#pragma unroll
            for (int rg = 0; rg < 4; ++rg) {
                const float v = acc[nt][rg];
                const u16 h = f2bf(v);
                const size_t o = (size_t)(orow + rg) * DD + nc0 + nt * 16 + l15;
                H[o] = h;
                L[o] = f2bf(v - bf2f(h));
            }
    }
}

// ---------------- flash kernel ----------------
// grid (128 row-tiles, 4 col-chunks). 4 waves; wave owns 16 rows. BR=64, BC=64.
__global__ __launch_bounds__(256, 2) void flash_kernel(
    const u16* __restrict__ Qh, const u16* __restrict__ Ql,
    const u16* __restrict__ Kh, const u16* __restrict__ Kl,
    const u16* __restrict__ Vt, const int* __restrict__ A,
    float* __restrict__ pO, float* __restrict__ pM, float* __restrict__ pL) {
    // K chunk: one plane (hi or lo), [64 j][64 k] bf16, XOR-swizzled 16B blocks, dbuf
    __shared__ u16 Klds[2][BC * 64];       // 16 KB
    __shared__ u16 Vlds[DD * BC];          // 32 KB, [n][j] swizzled
    __shared__ u16 Plds[4][16 * 72];       // 9 KB, per-wave, padded stride 72
    const int tid = threadIdx.x;
    const int lane = tid & 63;
    const int w = tid >> 6;
    const int l15 = lane & 15;
    const int quad = lane >> 4;
    const int r0 = blockIdx.x * BR;
    const int cch = blockIdx.y;
    const int col0 = cch * COLS;

    // Q fragments resident in registers (A-operand layout: m=lane&15, k=quad*8+i)
    bf16x8 qh[8], ql[8];
    {
        const size_t qbase = (size_t)(r0 + w * 16 + l15) * DD + quad * 8;
#pragma unroll
        for (int k = 0; k < 8; ++k) {
            qh[k] = *(const bf16x8*)(Qh + qbase + k * 32);
            ql[k] = *(const bf16x8*)(Ql + qbase + k * 32);
        }
    }

    const f32x4 fzero = {0.f, 0.f, 0.f, 0.f};
    f32x4 accO[16];
#pragma unroll
    for (int i = 0; i < 16; ++i) accO[i] = fzero;
    float mrow[4], lrow[4];
#pragma unroll
    for (int r = 0; r < 4; ++r) {
        mrow[r] = -1e30f;
        lrow[r] = 0.f;
    }

    auto stageK = [&](int phase, int j0, int buf) {
        const int kc = phase >> 1;
        const u16* src = (phase & 1) ? Kl : Kh;
#pragma unroll
        for (int i = 0; i < 2; ++i) {
            const int r = w * 16 + i * 8 + (lane >> 3);
            const int cb = (lane & 7) ^ (r & 7);
            gl2lds16(src + (size_t)(j0 + r) * DD + kc * 64 + cb * 8,
                     &Klds[buf][(w * 16 + i * 8) * 64]);
        }
    };
    auto stageV = [&](int j0) {
#pragma unroll
        for (int i = 0; i < 8; ++i) {
            const int n = w * 64 + i * 8 + (lane >> 3);
            const int jb = (lane & 7) ^ (n & 7);
            gl2lds16(Vt + (size_t)n * NN + j0 + jb * 8, &Vlds[(w * 64 + i * 8) * 64]);
        }
    };

    for (int it = 0; it < NIT; ++it) {
        const int j0 = col0 + it * BC;

        // adjacency loads for this tile (C-layout: row=quad*4+rg, col=jt*16+l15)
        int av[4][4];
#pragma unroll
        for (int jt = 0; jt < 4; ++jt)
#pragma unroll
            for (int rg = 0; rg < 4; ++rg)
                av[jt][rg] = A[(size_t)(r0 + w * 16 + quad * 4 + rg) * NN + j0 + jt * 16 + l15];

        stageV(j0);
        stageK(0, j0, 0);
        __syncthreads();

        f32x4 accS[4];
#pragma unroll
        for (int jt = 0; jt < 4; ++jt) accS[jt] = fzero;

        // 8 phases: (kc 0..3) x (hi, lo plane); dbuf pipelined
#pragma unroll
        for (int p = 0; p < 8; ++p) {
            if (p < 7) stageK(p + 1, j0, (p + 1) & 1);
            const int buf = p & 1;
            const int kc = p >> 1;
#pragma unroll
            for (int ks = 0; ks < 2; ++ks) {
                const int kidx = kc * 2 + ks;
#pragma unroll
                for (int jt = 0; jt < 4; ++jt) {
                    const int r = jt * 16 + l15;
                    const int cb = ks * 4 + quad;
                    const bf16x8 kf = *(const bf16x8*)&Klds[buf][(r * 8 + (cb ^ (r & 7))) * 8];
                    accS[jt] = MFMA16(qh[kidx], kf, accS[jt]);  // Qh*Kh or Qh*Kl
                    if ((p & 1) == 0)
                        accS[jt] = MFMA16(ql[kidx], kf, accS[jt]);  // Ql*Kh
                }
            }
            __syncthreads();
        }

        // mask + online softmax (per-reg row state, reduce over lane&15)
        float alpha[4];
#pragma unroll
        for (int rg = 0; rg < 4; ++rg) {
            const int grow = r0 + w * 16 + quad * 4 + rg;
            float mx = -3.0e38f;
#pragma unroll
            for (int jt = 0; jt < 4; ++jt) {
                const int gcol = j0 + jt * 16 + l15;
                float s = accS[jt][rg];
                s = (av[jt][rg] != 0 || grow == gcol) ? s : -3.0e38f;
                accS[jt][rg] = s;
                mx = fmaxf(mx, s);
            }
#pragma unroll
            for (int off = 1; off < 16; off <<= 1) mx = fmaxf(mx, __shfl_xor(mx, off, 64));
            const float mnew = fmaxf(mrow[rg], mx);
            alpha[rg] = __expf(mrow[rg] - mnew);
            float rs = 0.f;
#pragma unroll
            for (int jt = 0; jt < 4; ++jt) {
                const float e = __expf(accS[jt][rg] - mnew);  // masked -> exactly 0
                rs += e;
                Plds[w][(quad * 4 + rg) * 72 + jt * 16 + l15] = f2bf(e);
            }
#pragma unroll
            for (int off = 1; off < 16; off <<= 1) rs += __shfl_xor(rs, off, 64);
            lrow[rg] = lrow[rg] * alpha[rg] + rs;
            mrow[rg] = mnew;
        }
#pragma unroll
        for (int nt = 0; nt < 16; ++nt)
#pragma unroll
            for (int rg = 0; rg < 4; ++rg) accO[nt][rg] *= alpha[rg];

        // P (A-layout via per-wave LDS round trip) @ V
        bf16x8 pf[2];
#pragma unroll
        for (int kk = 0; kk < 2; ++kk)
            pf[kk] = *(const bf16x8*)&Plds[w][l15 * 72 + kk * 32 + quad * 8];
#pragma unroll
        for (int nt = 0; nt < 16; ++nt) {
#pragma unroll
            for (int kk = 0; kk < 2; ++kk) {
                const int n = nt * 16 + l15;
                const int cb = kk * 4 + quad;
                const bf16x8 vf = *(const bf16x8*)&Vlds[(n * 8 + (cb ^ (n & 7))) * 8];
                accO[nt] = MFMA16(pf[kk], vf, accO[nt]);
            }
        }
        __syncthreads();  // protect Vlds/Klds before next iter's staging
    }

    // write partials (unnormalized O, m, l)
#pragma unroll
    for (int nt = 0; nt < 16; ++nt)
#pragma unroll
        for (int rg = 0; rg < 4; ++rg) {
            const int grow = r0 + w * 16 + quad * 4 + rg;
            pO[((size_t)cch * NN + grow) * DD + nt * 16 + l15] = accO[nt][rg];
        }
    if (l15 == 0) {
#pragma unroll
        for (int rg = 0; rg < 4; ++rg) {
            const int grow = r0 + w * 16 + quad * 4 + rg;
            pM[(size_t)cch * NN + grow] = mrow[rg];
            pL[(size_t)cch * NN + grow] = lrow[rg];
        }
    }
}

// ---------------- merge partials ----------------
__global__ __launch_bounds__(256) void merge_kernel(const float* __restrict__ pO,
                                                    const float* __restrict__ pM,
                                                    const float* __restrict__ pL,
                                                    float* __restrict__ out) {
    const int row = blockIdx.x;
    const int n = threadIdx.x;
    float mc[CCH], lc[CCH];
    float M = -3e38f;
#pragma unroll
    for (int c = 0; c < CCH; ++c) {
        mc[c] = pM[(size_t)c * NN + row];
        lc[c] = pL[(size_t)c * NN + row];
        M = fmaxf(M, mc[c]);
    }
    float L = 0.f, acc = 0.f;
#pragma unroll
    for (int c = 0; c < CCH; ++c) {
        const float wgt = __expf(mc[c] - M);
        L += wgt * lc[c];
        acc += wgt * pO[((size_t)c * NN + row) * DD + n];
    }
    out[(size_t)row * DD + n] = acc / L;
}

extern "C" void kernel_launch(void* const* d_in, const int* in_sizes, int n_in,
                              void* d_out, int out_size, void* d_ws, size_t ws_size,
                              hipStream_t stream) {
    const float* X = (const float*)d_in[0];
    const int* A = (const int*)d_in[1];
    const float* Wq = (const float*)d_in[2];
    const float* Wk = (const float*)d_in[3];
    const float* Wv = (const float*)d_in[4];
    float* out = (float*)d_out;

    char* ws = (char*)d_ws;
    const size_t MB = 1ull << 20;
    u16* Xh = (u16*)(ws + 0 * MB);
    u16* Xl = (u16*)(ws + 4 * MB);
    u16* WtH = (u16*)(ws + 8 * MB);
    u16* WtL = (u16*)(ws + 8 * MB + 512 * 1024);
    u16* Qh = (u16*)(ws + 9 * MB);
    u16* Ql = (u16*)(ws + 13 * MB);
    u16* Kh = (u16*)(ws + 17 * MB);
    u16* Kl = (u16*)(ws + 21 * MB);
    u16* Vt = (u16*)(ws + 25 * MB);
    float* pO = (float*)(ws + 29 * MB);
    float* pM = (float*)(ws + 61 * MB);
    float* pL = (float*)(ws + 61 * MB + 256 * 1024);
    (void)ws_size; (void)in_sizes; (void)n_in; (void)out_size;

    splitX_kernel<<<(NN * DD + 255) / 256, 256, 0, stream>>>(X, Xh, Xl, NN * DD);
    splitW_kernel<<<(3 * 256 * 256) / 256, 256, 0, stream>>>(Wq, Wk, Wv, WtH, WtL);
    qkv_kernel<<<dim3(NN / 64, 12), 256, 0, stream>>>(Xh, Xl, WtH, WtL, Qh, Ql, Kh, Kl, Vt);
    flash_kernel<<<dim3(NN / BR, CCH), 256, 0, stream>>>(Qh, Ql, Kh, Kl, Vt, A, pO, pM, pL);
    merge_kernel<<<dim3(NN), 256, 0, stream>>>(pO, pM, pL, out);
}